// Round 20
// baseline (855.063 us; speedup 1.0000x reference)
//
#include <hip/hip_runtime.h>
#include <math.h>

#define NB 32
#define NT 16
#define NH 768
#define NV 32000

typedef short bf16x8 __attribute__((ext_vector_type(8)));
typedef float floatx4 __attribute__((ext_vector_type(4)));
typedef unsigned short ushort_t;

__device__ __forceinline__ float bf2f(unsigned short h) {
    unsigned u = ((unsigned)h) << 16;
    return __builtin_bit_cast(float, u);
}
__device__ __forceinline__ unsigned short f2bf(float f) {
    unsigned u = __builtin_bit_cast(unsigned, f);
    u += 0x7fffu + ((u >> 16) & 1u);
    return (unsigned short)(u >> 16);
}
__device__ __forceinline__ float sigmoidf_(float x) { return 1.f / (1.f + expf(-x)); }

// XCD-chunk swizzle: grid size N % 8 == 0.
__device__ __forceinline__ int swz8(int bid, int N) {
    return (bid & 7) * (N >> 3) + (bid >> 3);
}

__device__ __forceinline__ bf16x8 cvt8(float4 a, float4 b) {
    bf16x8 t;
    t[0] = (short)f2bf(a.x); t[1] = (short)f2bf(a.y);
    t[2] = (short)f2bf(a.z); t[3] = (short)f2bf(a.w);
    t[4] = (short)f2bf(b.x); t[5] = (short)f2bf(b.y);
    t[6] = (short)f2bf(b.z); t[7] = (short)f2bf(b.w);
    return t;
}

// ---------------- ONE merged prep kernel ----------------
#define SEG0 1216
#define SEG1 (SEG0 + 10240)
#define SEG2 (SEG1 + 73728)
#define SEG3 (SEG2 + 294912)
#define SEG4 (SEG3 + 1769472)
#define SEG5 (SEG4 + 589824)
#define SEG6 (SEG5 + 4718592)
#define SEG7 (SEG6 + 294912)
#define SEG8 (SEG7 + 393216)
#define SEG9 (SEG8 + 49152)
__global__ __launch_bounds__(256) void prep_all(
    const float* __restrict__ g1, const float* __restrict__ b1, const float* __restrict__ m1, const float* __restrict__ v1,
    const float* __restrict__ g2, const float* __restrict__ b2, const float* __restrict__ m2, const float* __restrict__ v2,
    const float* __restrict__ g3, const float* __restrict__ b3, const float* __restrict__ m3, const float* __restrict__ v3,
    const float* __restrict__ g4, const float* __restrict__ b4, const float* __restrict__ m4, const float* __restrict__ v4,
    float* __restrict__ s1, float* __restrict__ o1, float* __restrict__ s2, float* __restrict__ o2,
    float* __restrict__ s3, float* __restrict__ o3, float* __restrict__ s4, float* __restrict__ o4,
    const float* __restrict__ conv1_w, ushort_t* __restrict__ wb1,
    const float* __restrict__ conv2_w, ushort_t* __restrict__ wb2,
    const float* __restrict__ conv3_w, ushort_t* __restrict__ wb3,
    const float* __restrict__ conv4_w, ushort_t* __restrict__ wb4,
    const float* __restrict__ attn_w, ushort_t* __restrict__ wattnTP,
    const float* __restrict__ w_ih, const float* __restrict__ w_hh, ushort_t* __restrict__ wcombP,
    ushort_t* __restrict__ wihL,
    const int* __restrict__ caps, const float* __restrict__ table, ushort_t* __restrict__ e512P,
    float* __restrict__ hbuf, float* __restrict__ cbuf, ushort_t* __restrict__ xinA,
    unsigned long long* __restrict__ halo, long long n8) {
    long long gi = (long long)blockIdx.x * 256 + threadIdx.x;
    if (gi < SEG0) {
        int i = (int)gi;
        const float *g, *b, *m, *v;
        float *s, *o;
        int c;
        if (i < 64)        { g = g1; b = b1; m = m1; v = v1; s = s1; o = o1; c = i; }
        else if (i < 192)  { g = g2; b = b2; m = m2; v = v2; s = s2; o = o2; c = i - 64; }
        else if (i < 448)  { g = g3; b = b3; m = m3; v = v3; s = s3; o = o3; c = i - 192; }
        else               { g = g4; b = b4; m = m4; v = v4; s = s4; o = o4; c = i - 448; }
        float inv = g[c] * rsqrtf(v[c] + 1e-5f);
        s[c] = inv;
        o[c] = b[c] - m[c] * inv;
    } else if (gi < SEG1) {
        int idx = (int)(gi - SEG0);
        int co = idx / 160, k = idx % 160;
        wb1[idx] = (k < 147) ? f2bf(conv1_w[co * 147 + k]) : (ushort_t)0;
    } else if (gi < SEG4) {
        const float* w;
        ushort_t* dst;
        int CIN, idx;
        if (gi < SEG2)      { w = conv2_w; dst = wb2; CIN = 64;  idx = (int)(gi - SEG1); }
        else if (gi < SEG3) { w = conv3_w; dst = wb3; CIN = 128; idx = (int)(gi - SEG2); }
        else                { w = conv4_w; dst = wb4; CIN = 256; idx = (int)(gi - SEG3); }
        int e = idx & 7, lane = (idx >> 3) & 63, j = (idx >> 9) & 3;
        int r = idx >> 11;
        int KQ = CIN >> 5;
        int kq = r % KQ; r /= KQ;
        int tap = r % 9; int nt = r / 9;
        int co = nt * 64 + j * 16 + (lane & 15);
        int ci = kq * 32 + (lane >> 4) * 8 + e;
        dst[idx] = f2bf(w[((size_t)co * CIN + ci) * 9 + tap]);
    } else if (gi < SEG5) {
        int idx = (int)(gi - SEG4);
        int e = idx & 7, lane = (idx >> 3) & 63, j = (idx >> 9) & 3;
        int t = idx >> 11;
        int kq = t % 24, nt = t / 24;
        int n = nt * 64 + 16 * j + (lane & 15);
        int k = kq * 32 + (lane >> 4) * 8 + e;
        wattnTP[idx] = f2bf(attn_w[(size_t)k * 768 + n]);
    } else if (gi < SEG6) {
        int idx = (int)(gi - SEG5);
        int e = idx & 7, lane = (idx >> 3) & 63;
        int t = idx >> 9;
        int kq = t % 48, gg = t / 48;
        int g = gg & 3, bx = gg >> 2;
        int j = g * 768 + bx * 16 + (lane & 15);
        int k = kq * 32 + (lane >> 4) * 8 + e;
        float v = (k < NH) ? w_ih[(size_t)j * (2 * NH) + NH + k] : w_hh[(size_t)j * NH + (k - NH)];
        wcombP[idx] = f2bf(v);
    } else if (gi < SEG7) {
        int idx = (int)(gi - SEG6);
        int r = idx / 96, g = idx % 96;
        const float4* s = (const float4*)(w_ih + (size_t)r * 1536 + g * 8);
        *(bf16x8*)(wihL + (size_t)idx * 8) = cvt8(s[0], s[1]);
    } else if (gi < SEG8) {
        int idx = (int)(gi - SEG7);
        int e = idx & 7, lane = (idx >> 3) & 63, i = (idx >> 9) & 3;
        int t2 = idx >> 11;
        int kq = t2 % 24, mt = t2 / 24;
        int r = mt * 64 + i * 16 + (lane & 15);
        int k = kq * 32 + (lane >> 4) * 8 + e;
        int t = r >> 5, b = r & 31;
        e512P[idx] = f2bf(table[(size_t)caps[b * NT + t] * NH + k]);
    } else if (gi < SEG9) {
        int i = (int)(gi - SEG8);
        xinA[i] = 0;
        if (i < NB * NH) { hbuf[i] = 0.f; cbuf[i] = 0.f; }
    } else {
        long long j = gi - SEG9;
        if (j < n8) halo[j] = 0ULL;
    }
}

// ---------------- conv1 im2col ----------------
__global__ __launch_bounds__(256) void im2col1(const float* __restrict__ img, ushort_t* __restrict__ A) {
    int idx = blockIdx.x * 256 + threadIdx.x;
    const int total = 121856 * 160;
    if (idx >= total) return;
    int k = idx % 160;
    int m = idx / 160;
    ushort_t v = 0;
    if (k < 147) {
        int b = m / 3808;
        int rm = m % 3808;
        int y = rm / 112, x = rm % 112;
        int ci = k / 49;
        int r = k % 49;
        int ky = r / 7, kx = r % 7;
        int iy = 2 * y - 3 + ky;
        int ix = 2 * x - 3 + kx;
        if ((unsigned)iy < 224u && (unsigned)ix < 224u)
            v = f2bf(img[((size_t)(b * 3 + ci) * 224 + iy) * 224 + ix]);
    }
    A[idx] = v;
}

// rows of f32 -> bf16 (fc weights)
__global__ __launch_bounds__(256) void cvt_b16rows(const float* __restrict__ src, ushort_t* __restrict__ dst,
                                                   int cols8, int ldsrc, int total8) {
    int i = blockIdx.x * 256 + threadIdx.x;
    if (i >= total8) return;
    int r = i / cols8, g = i % cols8;
    const float4* s = (const float4*)(src + (size_t)r * ldsrc + g * 8);
    *(bf16x8*)(dst + (size_t)i * 8) = cvt8(s[0], s[1]);
}

// ---------------- conv1 GEMM ----------------
__global__ __launch_bounds__(256) void conv1_gemm(
    const ushort_t* __restrict__ A, const ushort_t* __restrict__ Bw,
    const float* __restrict__ scale, const float* __restrict__ bias,
    ushort_t* __restrict__ out) {
    int lane = threadIdx.x & 63, w = threadIdx.x >> 6;
    int m0 = (blockIdx.x * 4 + w) * 64;
    int lr = lane & 15, kl = (lane >> 4) * 8;
    floatx4 acc[4][4];
    #pragma unroll
    for (int i = 0; i < 4; ++i)
        #pragma unroll
        for (int j = 0; j < 4; ++j) acc[i][j] = 0.f;
    #pragma unroll
    for (int k0 = 0; k0 < 160; k0 += 32) {
        bf16x8 a[4], bb[4];
        #pragma unroll
        for (int i = 0; i < 4; ++i) a[i] = *(const bf16x8*)(A + (size_t)(m0 + 16 * i + lr) * 160 + kl + k0);
        #pragma unroll
        for (int j = 0; j < 4; ++j) bb[j] = *(const bf16x8*)(Bw + (size_t)(16 * j + lr) * 160 + kl + k0);
        #pragma unroll
        for (int i = 0; i < 4; ++i)
            #pragma unroll
            for (int j = 0; j < 4; ++j)
                acc[i][j] = __builtin_amdgcn_mfma_f32_16x16x32_bf16(a[i], bb[j], acc[i][j], 0, 0, 0);
    }
    #pragma unroll
    for (int i = 0; i < 4; ++i) {
        #pragma unroll
        for (int r = 0; r < 4; ++r) {
            int m = m0 + 16 * i + (lane >> 4) * 4 + r;
            int b = m / 3808;
            int rm = m % 3808;
            int y = rm / 112, x = rm % 112;
            #pragma unroll
            for (int j = 0; j < 4; ++j) {
                int n = 16 * j + lr;
                float v = fmaxf(acc[i][j][r] * scale[n] + bias[n], 0.f);
                out[((size_t)(b * 34 + y) * 112 + x) * 64 + n] = f2bf(v);
            }
        }
    }
}

// ---------------- maxpool 3x3 s2 p1 ----------------
__global__ __launch_bounds__(256) void pool_kernel(const ushort_t* __restrict__ in,
                                                   ushort_t* __restrict__ hal2) {
    int idx = blockIdx.x * 256 + threadIdx.x;
    const int total = 32 * 17 * 56 * 8;
    if (idx >= total) return;
    int c8 = idx & 7;
    int rest = idx >> 3;
    int x = rest % 56; rest /= 56;
    int y = rest % 17; int b = rest / 17;
    float mx[8];
    #pragma unroll
    for (int j = 0; j < 8; ++j) mx[j] = -INFINITY;
    for (int dy = -1; dy <= 1; ++dy) {
        int iy = 2 * y + dy;
        if ((unsigned)iy >= 34u) continue;
        for (int dx = -1; dx <= 1; ++dx) {
            int ix = 2 * x + dx;
            if ((unsigned)ix >= 112u) continue;
            bf16x8 v = *(const bf16x8*)(in + (((size_t)(b * 34 + iy)) * 112 + ix) * 64 + c8 * 8);
            #pragma unroll
            for (int j = 0; j < 8; ++j) mx[j] = fmaxf(mx[j], bf2f((unsigned short)v[j]));
        }
    }
    bf16x8 o;
    #pragma unroll
    for (int j = 0; j < 8; ++j) o[j] = (short)f2bf(mx[j]);
    *(bf16x8*)(hal2 + (((size_t)(b * 19 + y + 1)) * 58 + (x + 1)) * 64 + c8 * 8) = o;
}

// ---------------- conv2: 2-wave LDS-staged-A, PHASE=3 (NK=18, 6 phases) ----------------
// grid 448, block 128. Wave w -> nt = w (COUT=128). Staging: 2 thr/row, 2x16B chunks.
__global__ __launch_bounds__(128) void conv2_lds(
    const ushort_t* __restrict__ in, const ushort_t* __restrict__ wtP,
    const float* __restrict__ scale, const float* __restrict__ bias,
    ushort_t* __restrict__ out) {
    const int CIN = 64, WH = 58;
    __shared__ ushort_t at[2][3 * 2560];
    int tid = threadIdx.x;
    int lane = tid & 63, w = tid >> 6;       // w in 0..1
    int mt = swz8(blockIdx.x, 448);
    int nt = w;
    int lr = lane & 15, kl = (lane >> 4) * 8;
    int srow = tid >> 1, sc = tid & 1;       // 2 chunks of 8 bf16 at cols sc*16, sc*16+8
    int m_s = mt * 64 + srow;
    int b_s = m_s / 896, rm_s = m_s % 896;
    int y_s = rm_s / 56, x_s = rm_s % 56;
    const ushort_t* arow = in + ((size_t)(b_s * 19 + y_s) * 58 + x_s) * CIN + sc * 16;
    int woff = srow * 40 + sc * 16;

    floatx4 acc[4][4];
    #pragma unroll
    for (int i = 0; i < 4; ++i)
        #pragma unroll
        for (int j = 0; j < 4; ++j) acc[i][j] = 0.f;

    auto ioffOf = [&](int ks) {
        int tap = ks >> 1;
        int k0 = (ks & 1) * 32;
        int ky = tap / 3, kx = tap - ky * 3;
        return (ky * WH + kx) * CIN + k0;
    };
    const ushort_t* bbase = wtP + ((size_t)nt * 18 * 4 * 64 + lane) * 8;

    bf16x8 st[3][2];
    #pragma unroll
    for (int j = 0; j < 3; ++j) {
        int io = ioffOf(j);
        st[j][0] = *(const bf16x8*)(arow + io);
        st[j][1] = *(const bf16x8*)(arow + io + 8);
    }
    for (int p = 0; p < 6; ++p) {
        ushort_t* buf = &at[p & 1][0];
        #pragma unroll
        for (int j = 0; j < 3; ++j) {
            *(bf16x8*)(buf + j * 2560 + woff) = st[j][0];
            *(bf16x8*)(buf + j * 2560 + woff + 8) = st[j][1];
        }
        if (p < 5) {
            #pragma unroll
            for (int j = 0; j < 3; ++j) {
                int io = ioffOf((p + 1) * 3 + j);
                st[j][0] = *(const bf16x8*)(arow + io);
                st[j][1] = *(const bf16x8*)(arow + io + 8);
            }
        }
        __syncthreads();
        #pragma unroll
        for (int kk = 0; kk < 3; ++kk) {
            int ks = p * 3 + kk;
            bf16x8 a[4], bb[4];
            #pragma unroll
            for (int j = 0; j < 4; ++j)
                bb[j] = *(const bf16x8*)(bbase + ((size_t)(ks * 4 + j) * 64) * 8);
            #pragma unroll
            for (int i = 0; i < 4; ++i)
                a[i] = *(const bf16x8*)(buf + kk * 2560 + (16 * i + lr) * 40 + kl);
            #pragma unroll
            for (int i = 0; i < 4; ++i)
                #pragma unroll
                for (int j = 0; j < 4; ++j)
                    acc[i][j] = __builtin_amdgcn_mfma_f32_16x16x32_bf16(a[i], bb[j], acc[i][j], 0, 0, 0);
        }
        __syncthreads();
    }
    #pragma unroll
    for (int i = 0; i < 4; ++i) {
        #pragma unroll
        for (int r = 0; r < 4; ++r) {
            int m = mt * 64 + 16 * i + (lane >> 4) * 4 + r;
            int b = m / 896, rm = m % 896;
            int y = rm / 56, x = rm % 56;
            #pragma unroll
            for (int j = 0; j < 4; ++j) {
                int n = nt * 64 + 16 * j + lr;
                float v = fmaxf(acc[i][j][r] * scale[n] + bias[n], 0.f);
                out[((size_t)(b * 18 + y + 1) * 58 + (x + 1)) * 128 + n] = f2bf(v);
            }
        }
    }
}

// ---------------- conv3: 4-wave LDS-staged-A, PHASE=4 (NK=36, 9 phases), stride 2 ----------------
// grid 112, block 256. Wave w -> nt = w (COUT=256).
__global__ __launch_bounds__(256) void conv3_lds(
    const ushort_t* __restrict__ in, const ushort_t* __restrict__ wtP,
    const float* __restrict__ scale, const float* __restrict__ bias,
    ushort_t* __restrict__ out) {
    const int CIN = 128, WH = 58;
    __shared__ ushort_t at[2][4 * 2560];
    int tid = threadIdx.x;
    int lane = tid & 63, w = tid >> 6;
    int mt = swz8(blockIdx.x, 112);
    int nt = w;
    int lr = lane & 15, kl = (lane >> 4) * 8;
    int srow = tid >> 2, sc = tid & 3;
    int m_s = mt * 64 + srow;
    int b_s = m_s / 224, rm_s = m_s % 224;
    int y_s = rm_s / 28, x_s = rm_s % 28;
    const ushort_t* arow = in + ((size_t)(b_s * 18 + y_s * 2) * 58 + x_s * 2) * CIN + sc * 8;
    int woff = srow * 40 + sc * 8;

    floatx4 acc[4][4];
    #pragma unroll
    for (int i = 0; i < 4; ++i)
        #pragma unroll
        for (int j = 0; j < 4; ++j) acc[i][j] = 0.f;

    auto ioffOf = [&](int ks) {
        int tap = ks >> 2;
        int k0 = (ks & 3) * 32;
        int ky = tap / 3, kx = tap - ky * 3;
        return (ky * WH + kx) * CIN + k0;
    };
    const ushort_t* bbase = wtP + ((size_t)nt * 36 * 4 * 64 + lane) * 8;

    bf16x8 st[4];
    #pragma unroll
    for (int j = 0; j < 4; ++j) st[j] = *(const bf16x8*)(arow + ioffOf(j));
    for (int p = 0; p < 9; ++p) {
        ushort_t* buf = &at[p & 1][0];
        #pragma unroll
        for (int j = 0; j < 4; ++j)
            *(bf16x8*)(buf + j * 2560 + woff) = st[j];
        if (p < 8) {
            #pragma unroll
            for (int j = 0; j < 4; ++j)
                st[j] = *(const bf16x8*)(arow + ioffOf((p + 1) * 4 + j));
        }
        __syncthreads();
        #pragma unroll
        for (int kk = 0; kk < 4; ++kk) {
            int ks = p * 4 + kk;
            bf16x8 a[4], bb[4];
            #pragma unroll
            for (int j = 0; j < 4; ++j)
                bb[j] = *(const bf16x8*)(bbase + ((size_t)(ks * 4 + j) * 64) * 8);
            #pragma unroll
            for (int i = 0; i < 4; ++i)
                a[i] = *(const bf16x8*)(buf + kk * 2560 + (16 * i + lr) * 40 + kl);
            #pragma unroll
            for (int i = 0; i < 4; ++i)
                #pragma unroll
                for (int j = 0; j < 4; ++j)
                    acc[i][j] = __builtin_amdgcn_mfma_f32_16x16x32_bf16(a[i], bb[j], acc[i][j], 0, 0, 0);
        }
        __syncthreads();
    }
    #pragma unroll
    for (int i = 0; i < 4; ++i) {
        #pragma unroll
        for (int r = 0; r < 4; ++r) {
            int m = mt * 64 + 16 * i + (lane >> 4) * 4 + r;
            int b = m / 224, rm = m % 224;
            int y = rm / 28, x = rm % 28;
            #pragma unroll
            for (int j = 0; j < 4; ++j) {
                int n = nt * 64 + 16 * j + lr;
                float v = fmaxf(acc[i][j][r] * scale[n] + bias[n], 0.f);
                out[((size_t)(b * 10 + y + 1) * 30 + (x + 1)) * 256 + n] = f2bf(v);
            }
        }
    }
}

// ---------------- conv4: 4-wave LDS-staged-A, PHASE=4 ----------------
__global__ __launch_bounds__(256) void conv4_lds(
    const ushort_t* __restrict__ in, const ushort_t* __restrict__ wtP,
    const float* __restrict__ scale, const float* __restrict__ bias,
    ushort_t* __restrict__ memv) {
    const int CIN = 256, WH = 30;
    __shared__ ushort_t at[2][4 * 64 * 40];
    int tid = threadIdx.x;
    int lane = tid & 63, w = tid >> 6;
    int mt = blockIdx.x;
    int nt = blockIdx.y * 4 + w;
    int lr = lane & 15, kl = (lane >> 4) * 8;
    int srow = tid >> 2, sc = tid & 3;
    int m_s = mt * 64 + srow;
    int b_s = m_s / 196, rm_s = m_s % 196;
    int y_s = rm_s / 28, x_s = rm_s % 28;
    const ushort_t* arow = in + ((size_t)(b_s * 10 + y_s) * 30 + x_s) * CIN + sc * 8;
    int woff = srow * 40 + sc * 8;

    floatx4 acc[4][4];
    #pragma unroll
    for (int i = 0; i < 4; ++i)
        #pragma unroll
        for (int j = 0; j < 4; ++j) acc[i][j] = 0.f;

    auto ioffOf = [&](int ks) {
        int tap = ks >> 3;
        int k0 = (ks & 7) * 32;
        int ky = tap / 3, kx = tap - ky * 3;
        return (ky * WH + kx) * CIN + k0;
    };
    const ushort_t* bbase = wtP + ((size_t)nt * 72 * 4 * 64 + lane) * 8;

    bf16x8 st[4];
    #pragma unroll
    for (int j = 0; j < 4; ++j) st[j] = *(const bf16x8*)(arow + ioffOf(j));
    for (int p = 0; p < 18; ++p) {
        ushort_t* buf = &at[p & 1][0];
        #pragma unroll
        for (int j = 0; j < 4; ++j)
            *(bf16x8*)(buf + j * 2560 + woff) = st[j];
        if (p < 17) {
            #pragma unroll
            for (int j = 0; j < 4; ++j)
                st[j] = *(const bf16x8*)(arow + ioffOf((p + 1) * 4 + j));
        }
        __syncthreads();
        #pragma unroll
        for (int kk = 0; kk < 4; ++kk) {
            int ks = p * 4 + kk;
            bf16x8 a[4], bb[4];
            #pragma unroll
            for (int j = 0; j < 4; ++j)
                bb[j] = *(const bf16x8*)(bbase + ((size_t)(ks * 4 + j) * 64) * 8);
            #pragma unroll
            for (int i = 0; i < 4; ++i)
                a[i] = *(const bf16x8*)(buf + kk * 2560 + (16 * i + lr) * 40 + kl);
            #pragma unroll
            for (int i = 0; i < 4; ++i)
                #pragma unroll
                for (int j = 0; j < 4; ++j)
                    acc[i][j] = __builtin_amdgcn_mfma_f32_16x16x32_bf16(a[i], bb[j], acc[i][j], 0, 0, 0);
        }
        __syncthreads();
    }
    #pragma unroll
    for (int i = 0; i < 4; ++i) {
        #pragma unroll
        for (int r = 0; r < 4; ++r) {
            int m = mt * 64 + 16 * i + (lane >> 4) * 4 + r;
            #pragma unroll
            for (int j = 0; j < 4; ++j) {
                int n = nt * 64 + 16 * j + lr;
                float v = fmaxf(acc[i][j][r] * scale[n] + bias[n], 0.f);
                memv[(size_t)m * 768 + n] = f2bf(v);
            }
        }
    }
}

// ---------------- kmat: 4-wave LDS-staged-A; KT [b][96][196][8] ----------------
__global__ __launch_bounds__(256) void kmat_lds(
    const ushort_t* __restrict__ memv, const ushort_t* __restrict__ Bp,
    ushort_t* __restrict__ KT) {
    __shared__ ushort_t at[2][4 * 64 * 40];
    int tid = threadIdx.x;
    int lane = tid & 63, w = tid >> 6;
    int mt = blockIdx.x;
    int nt = blockIdx.y * 4 + w;
    int lr = lane & 15, kl = (lane >> 4) * 8;
    int srow = tid >> 2, sc = tid & 3;
    const ushort_t* arow = memv + (size_t)(mt * 64 + srow) * 768 + sc * 8;
    int woff = srow * 40 + sc * 8;
    const ushort_t* bbase = Bp + ((size_t)nt * 24 * 4 * 64 + lane) * 8;

    floatx4 acc[4][4];
    #pragma unroll
    for (int i = 0; i < 4; ++i)
        #pragma unroll
        for (int j = 0; j < 4; ++j) acc[i][j] = 0.f;

    bf16x8 st[4];
    #pragma unroll
    for (int j = 0; j < 4; ++j) st[j] = *(const bf16x8*)(arow + j * 32);
    for (int p = 0; p < 6; ++p) {
        ushort_t* buf = &at[p & 1][0];
        #pragma unroll
        for (int j = 0; j < 4; ++j)
            *(bf16x8*)(buf + j * 2560 + woff) = st[j];
        if (p < 5) {
            #pragma unroll
            for (int j = 0; j < 4; ++j)
                st[j] = *(const bf16x8*)(arow + ((p + 1) * 4 + j) * 32);
        }
        __syncthreads();
        #pragma unroll
        for (int kk = 0; kk < 4; ++kk) {
            int ks = p * 4 + kk;
            bf16x8 a[4], bb[4];
            #pragma unroll
            for (int j = 0; j < 4; ++j)
                bb[j] = *(const bf16x8*)(bbase + ((size_t)(ks * 4 + j) * 64) * 8);
            #pragma unroll
            for (int i = 0; i < 4; ++i)
                a[i] = *(const bf16x8*)(buf + kk * 2560 + (16 * i + lr) * 40 + kl);
            #pragma unroll
            for (int i = 0; i < 4; ++i)
                #pragma unroll
                for (int j = 0; j < 4; ++j)
                    acc[i][j] = __builtin_amdgcn_mfma_f32_16x16x32_bf16(a[i], bb[j], acc[i][j], 0, 0, 0);
        }
        __syncthreads();
    }
    #pragma unroll
    for (int i = 0; i < 4; ++i) {
        #pragma unroll
        for (int r = 0; r < 4; ++r) {
            int mg = mt * 64 + 16 * i + (lane >> 4) * 4 + r;
            int b = mg / 196, m = mg % 196;
            #pragma unroll
            for (int j = 0; j < 4; ++j) {
                int n = nt * 64 + 16 * j + lr;
                KT[(((size_t)b * 96 + (n >> 3)) * 196 + m) * 8 + (n & 7)] = f2bf(acc[i][j][r]);
            }
        }
    }
}

// ---------------- occupancy-first GEMM: C[512][N] = Ap . Bb^T + bias; swizzled 1D grid ----------------
// REMAP path also copies h/c into the output tail (block 0) -> saves a launch.
template <int REMAP>
__global__ __launch_bounds__(256, 4) void gemm_ldsb(
    const ushort_t* __restrict__ Ap, const ushort_t* __restrict__ Bb,
    const float* __restrict__ bias1, const float* __restrict__ bias2,
    float* __restrict__ C, int N,
    const float* __restrict__ hcp, const float* __restrict__ ccp) {
    __shared__ ushort_t bt[2][64 * 72];
    int tid = threadIdx.x;
    int lane = tid & 63, w = tid >> 6;
    int nblk = (N >> 6) * 2;
    int id = swz8(blockIdx.x, nblk);
    int nt = id >> 1, mh = id & 1;
    int n0 = nt * 64;
    int mt = mh * 4 + w;
    int lr = lane & 15, hi = lane >> 4;
    int srow = tid >> 2, sc = tid & 3;
    const ushort_t* gsrc = Bb + (size_t)(n0 + srow) * 768 + sc * 8;
    int woff = srow * 72 + sc * 8;
    floatx4 acc[4][4];
    #pragma unroll
    for (int i = 0; i < 4; ++i)
        #pragma unroll
        for (int j = 0; j < 4; ++j) acc[i][j] = 0.f;
    bf16x8 s0 = *(const bf16x8*)(gsrc);
    bf16x8 s1 = *(const bf16x8*)(gsrc + 32);
    for (int kc = 0; kc < 12; ++kc) {
        ushort_t* bufw = &bt[kc & 1][0];
        *(bf16x8*)(bufw + woff) = s0;
        *(bf16x8*)(bufw + woff + 32) = s1;
        if (kc < 11) {
            const ushort_t* p = gsrc + (size_t)(kc + 1) * 64;
            s0 = *(const bf16x8*)(p);
            s1 = *(const bf16x8*)(p + 32);
        }
        __syncthreads();
        const ushort_t* bufr = &bt[kc & 1][0];
        #pragma unroll
        for (int kk = 0; kk < 2; ++kk) {
            int kq = kc * 2 + kk;
            bf16x8 bfr[4], a[4];
            #pragma unroll
            for (int j = 0; j < 4; ++j)
                bfr[j] = *(const bf16x8*)(bufr + (j * 16 + lr) * 72 + kk * 32 + hi * 8);
            #pragma unroll
            for (int i = 0; i < 4; ++i)
                a[i] = *(const bf16x8*)(Ap + ((((size_t)mt * 24 + kq) * 4 + i) * 64 + lane) * 8);
            #pragma unroll
            for (int i = 0; i < 4; ++i)
                #pragma unroll
                for (int j = 0; j < 4; ++j)
                    acc[i][j] = __builtin_amdgcn_mfma_f32_16x16x32_bf16(a[i], bfr[j], acc[i][j], 0, 0, 0);
        }
    }
    #pragma unroll
    for (int i = 0; i < 4; ++i) {
        #pragma unroll
        for (int rr = 0; rr < 4; ++rr) {
            int m = mt * 64 + 16 * i + hi * 4 + rr;   // m = t*32+b
            #pragma unroll
            for (int j = 0; j < 4; ++j) {
                int n = n0 + 16 * j + lr;
                float vv = acc[i][j][rr];
                if (bias1) vv += bias1[n];
                if (bias2) vv += bias2[n];
                if (REMAP) {
                    int t = m >> 5, b = m & 31;
                    C[(size_t)((b << 4) + t) * NV + n] = vv;
                } else {
                    C[(size_t)m * N + n] = vv;
                }
            }
        }
    }
    if (REMAP && blockIdx.x == 0) {
        for (int i = tid; i < NB * NH; i += 256) {
            C[(size_t)NB * NT * NV + i] = hcp[i];
            C[(size_t)NB * NT * NV + NB * NH + i] = ccp[i];
        }
    }
}

// ---------------- attention step, 2-way split: grid (32, 2) ----------------
__global__ __launch_bounds__(768) void attn2(
    ushort_t* __restrict__ xin, const ushort_t* __restrict__ KT,
    const ushort_t* __restrict__ mem) {
    __shared__ float hq[NH];
    __shared__ float sl[196];
    __shared__ float red[16];
    int b = blockIdx.x, halfb = blockIdx.y, tid = threadIdx.x;
    hq[tid] = bf2f(xin[(size_t)b * 1536 + NH + tid]);
    __syncthreads();
    if (tid < 392) {
        int m = tid >> 1, half = tid & 1;
        const ushort_t* basep = KT + (((size_t)b * 96 + half * 48) * 196 + m) * 8;
        float acc = 0.f;
        #pragma unroll 4
        for (int k8 = 0; k8 < 48; ++k8) {
            bf16x8 v = *(const bf16x8*)(basep + (size_t)k8 * 196 * 8);
            const float* qp = hq + (half * 48 + k8) * 8;
            #pragma unroll
            for (int j = 0; j < 8; ++j)
                acc = fmaf(bf2f((unsigned short)v[j]), qp[j], acc);
        }
        acc += __shfl_xor(acc, 1);
        if (!half) sl[m] = acc;
    }
    __syncthreads();
    float sc = (tid < 196) ? sl[tid] : -INFINITY;
    float v = sc;
    #pragma unroll
    for (int off = 32; off; off >>= 1) v = fmaxf(v, __shfl_down(v, off));
    if ((tid & 63) == 0) red[tid >> 6] = v;
    __syncthreads();
    if (tid == 0) {
        float m = red[0];
        for (int i = 1; i < 12; ++i) m = fmaxf(m, red[i]);
        red[12] = m;
    }
    __syncthreads();
    float mx = red[12];
    float e = (tid < 196) ? expf(sc - mx) : 0.f;
    __syncthreads();
    v = e;
    #pragma unroll
    for (int off = 32; off; off >>= 1) v += __shfl_down(v, off);
    if ((tid & 63) == 0) red[tid >> 6] = v;
    __syncthreads();
    if (tid == 0) {
        float s = red[0];
        for (int i = 1; i < 12; ++i) s += red[i];
        red[12] = 1.f / s;
    }
    __syncthreads();
    if (tid < 196) sl[tid] = e * red[12];
    __syncthreads();
    if (tid < 384) {
        int d = halfb * 384 + tid;
        float acc = 0.f;
        const ushort_t* mb = mem + (size_t)b * 196 * NH + d;
        #pragma unroll 4
        for (int m = 0; m < 196; ++m) acc = fmaf(sl[m], bf2f(mb[(size_t)m * NH]), acc);
        xin[(size_t)b * 1536 + d] = f2bf(acc);
    }
}

// ---------------- fused gates GEMM + LSTM cell; writes Hall PACKED ----------------
__global__ __launch_bounds__(256) void step_fused(
    const ushort_t* __restrict__ xin_r, const ushort_t* __restrict__ wcombP,
    const float* __restrict__ eg_t,
    float* __restrict__ cbuf, float* __restrict__ hbuf,
    ushort_t* __restrict__ xin_w, ushort_t* __restrict__ hallP, int tstep) {
    __shared__ float pbuf[4][64][33];
    int lane = threadIdx.x & 63, w = threadIdx.x >> 6;
    int bx = blockIdx.x;
    int lr = lane & 15, kl = (lane >> 4) * 8;
    floatx4 acc[2][4];
    #pragma unroll
    for (int i = 0; i < 2; ++i)
        #pragma unroll
        for (int g = 0; g < 4; ++g) acc[i][g] = 0.f;
    for (int kq = 0; kq < 12; ++kq) {
        int k = w * 384 + kq * 32;
        bf16x8 a[2], bb[4];
        #pragma unroll
        for (int i = 0; i < 2; ++i)
            a[i] = *(const bf16x8*)(xin_r + (size_t)(16 * i + lr) * 1536 + k + kl);
        #pragma unroll
        for (int g = 0; g < 4; ++g)
            bb[g] = *(const bf16x8*)(wcombP + (((size_t)(bx * 4 + g) * 48 + (w * 12 + kq)) * 64 + lane) * 8);
        #pragma unroll
        for (int i = 0; i < 2; ++i)
            #pragma unroll
            for (int g = 0; g < 4; ++g)
                acc[i][g] = __builtin_amdgcn_mfma_f32_16x16x32_bf16(a[i], bb[g], acc[i][g], 0, 0, 0);
    }
    #pragma unroll
    for (int i = 0; i < 2; ++i)
        #pragma unroll
        for (int g = 0; g < 4; ++g)
            #pragma unroll
            for (int r = 0; r < 4; ++r) {
                int m = 16 * i + (lane >> 4) * 4 + r;
                pbuf[w][g * 16 + lr][m] = acc[i][g][r];
            }
    __syncthreads();
    int tid = threadIdx.x;
    #pragma unroll
    for (int o = 0; o < 2; ++o) {
        int pid = tid * 2 + o;
        int m = pid & 31, c = pid >> 5;
        int kcol = bx * 16 + c;
        float gi = 0.f, gf = 0.f, gg = 0.f, go = 0.f;
        #pragma unroll
        for (int ww = 0; ww < 4; ++ww) {
            gi += pbuf[ww][c][m];
            gf += pbuf[ww][16 + c][m];
            gg += pbuf[ww][32 + c][m];
            go += pbuf[ww][48 + c][m];
        }
        const float* eg = eg_t + (size_t)m * 3072;
        gi += eg[kcol];
        gf += eg[768 + kcol];
        gg += eg[1536 + kcol];
        go += eg[2304 + kcol];
        float cst = cbuf[m * 768 + kcol];
        float cn = sigmoidf_(gf) * cst + sigmoidf_(gi) * tanhf(gg);
        float hn = sigmoidf_(go) * tanhf(cn);
        cbuf[m * 768 + kcol] = cn;
        hbuf[m * 768 + kcol] = hn;
        ushort_t hb = f2bf(hn);
        xin_w[(size_t)m * 1536 + NH + kcol] = hb;
        int rrow = tstep * 32 + m;
        int mtp = rrow >> 6, ip = (rrow >> 4) & 3, lrp = rrow & 15;
        int kqp = kcol >> 5, hip = (kcol >> 3) & 3, ep = kcol & 7;
        hallP[((((size_t)mtp * 24 + kqp) * 4 + ip) * 64 + (lrp | (hip << 4))) * 8 + ep] = hb;
    }
}

extern "C" void kernel_launch(void* const* d_in, const int* in_sizes, int n_in,
                              void* d_out, int out_size, void* d_ws, size_t ws_size,
                              hipStream_t stream) {
    const float* images   = (const float*)d_in[0];
    const int*   captions = (const int*)d_in[1];
    const float* conv1_w  = (const float*)d_in[2];
    const float* bn1_g = (const float*)d_in[3], *bn1_b = (const float*)d_in[4];
    const float* bn1_m = (const float*)d_in[5], *bn1_v = (const float*)d_in[6];
    const float* conv2_w  = (const float*)d_in[7];
    const float* bn2_g = (const float*)d_in[8], *bn2_b = (const float*)d_in[9];
    const float* bn2_m = (const float*)d_in[10], *bn2_v = (const float*)d_in[11];
    const float* conv3_w  = (const float*)d_in[12];
    const float* bn3_g = (const float*)d_in[13], *bn3_b = (const float*)d_in[14];
    const float* bn3_m = (const float*)d_in[15], *bn3_v = (const float*)d_in[16];
    const float* conv4_w  = (const float*)d_in[17];
    const float* bn4_g = (const float*)d_in[18], *bn4_b = (const float*)d_in[19];
    const float* bn4_m = (const float*)d_in[20], *bn4_v = (const float*)d_in[21];
    const float* emb_table = (const float*)d_in[22];
    const float* attn_w   = (const float*)d_in[23];
    const float* w_ih     = (const float*)d_in[24];
    const float* w_hh     = (const float*)d_in[25];
    const float* b_ih     = (const float*)d_in[26];
    const float* b_hh     = (const float*)d_in[27];
    const float* fc_w     = (const float*)d_in[28];
    const float* fc_b     = (const float*)d_in[29];
    float* out = (float*)d_out;

    // ---- workspace layout ----
    char* base = (char*)d_ws;
    size_t off = 0;
    auto alloc = [&](size_t bytes) { char* p = base + off; off += (bytes + 255) & ~(size_t)255; return p; };
    float* s1 = (float*)alloc(64 * 4);   float* bb1 = (float*)alloc(64 * 4);
    float* s2 = (float*)alloc(128 * 4);  float* bb2 = (float*)alloc(128 * 4);
    float* s3 = (float*)alloc(256 * 4);  float* bb3 = (float*)alloc(256 * 4);
    float* s4 = (float*)alloc(768 * 4);  float* bb4 = (float*)alloc(768 * 4);
    ushort_t* c1out = (ushort_t*)alloc((size_t)32 * 34 * 112 * 64 * 2);
    size_t halo_start = off;
    ushort_t* hal2 = (ushort_t*)alloc((size_t)32 * 19 * 58 * 64 * 2);
    ushort_t* hal3 = (ushort_t*)alloc((size_t)32 * 18 * 58 * 128 * 2);
    ushort_t* hal4 = (ushort_t*)alloc((size_t)32 * 10 * 30 * 256 * 2);
    size_t halo_bytes = off - halo_start;
    ushort_t* memv = (ushort_t*)alloc((size_t)32 * 196 * 768 * 2);
    ushort_t* KT   = (ushort_t*)alloc((size_t)32 * 96 * 196 * 8 * 2);
    ushort_t* wb1 = (ushort_t*)alloc((size_t)64 * 160 * 2);
    ushort_t* wb2 = (ushort_t*)alloc((size_t)128 * 9 * 64 * 2);
    ushort_t* wb3 = (ushort_t*)alloc((size_t)256 * 9 * 128 * 2);
    ushort_t* wb4 = (ushort_t*)alloc((size_t)768 * 9 * 256 * 2);
    ushort_t* wattnTP = (ushort_t*)alloc((size_t)768 * 768 * 2);
    ushort_t* wcombP = (ushort_t*)alloc((size_t)3072 * 1536 * 2);
    ushort_t* wihL = (ushort_t*)alloc((size_t)3072 * 768 * 2);
    ushort_t* e512P = (ushort_t*)alloc((size_t)512 * 768 * 2);
    float* eg   = (float*)alloc((size_t)512 * 3072 * 4);
    ushort_t* HallP = (ushort_t*)alloc((size_t)512 * 768 * 2);
    float* hbuf = (float*)alloc(NB * NH * 4);
    float* cbuf = (float*)alloc(NB * NH * 4);
    ushort_t* xinA = (ushort_t*)alloc((size_t)NB * 1536 * 2);
    ushort_t* xinB = (ushort_t*)alloc((size_t)NB * 1536 * 2);
    // union: im2col (39 MB, dead after conv1_gemm) then fc_w bf16 (49.2 MB)
    char* ubig = alloc((size_t)NV * NH * 2);
    ushort_t* imcol = (ushort_t*)ubig;
    ushort_t* fcwb  = (ushort_t*)ubig;

    // ---- merged one-time transforms (1 launch) ----
    long long n8 = (long long)(halo_bytes / 8);
    long long prep_total = (long long)SEG9 + n8;
    prep_all<<<(unsigned)((prep_total + 255) / 256), 256, 0, stream>>>(
        bn1_g, bn1_b, bn1_m, bn1_v, bn2_g, bn2_b, bn2_m, bn2_v,
        bn3_g, bn3_b, bn3_m, bn3_v, bn4_g, bn4_b, bn4_m, bn4_v,
        s1, bb1, s2, bb2, s3, bb3, s4, bb4,
        conv1_w, wb1, conv2_w, wb2, conv3_w, wb3, conv4_w, wb4,
        attn_w, wattnTP, w_ih, w_hh, wcombP, wihL,
        captions, emb_table, e512P,
        hbuf, cbuf, xinA,
        (unsigned long long*)hal2, n8);

    // ---- decoder precompute GEMM (independent of encoder) ----
    gemm_ldsb<0><<<96, 256, 0, stream>>>(e512P, wihL, b_ih, b_hh, eg, 3072, nullptr, nullptr);

    // ---- encoder ----
    im2col1<<<(121856 * 160 + 255) / 256, 256, 0, stream>>>(images, imcol);
    conv1_gemm<<<476, 256, 0, stream>>>(imcol, wb1, s1, bb1, c1out);
    // imcol dead -> convert fc_w (f32->bf16 row-major) into same buffer
    cvt_b16rows<<<(NV * 96 + 255) / 256, 256, 0, stream>>>(fc_w, fcwb, 96, 768, NV * 96);
    pool_kernel<<<(32 * 17 * 56 * 8 + 255) / 256, 256, 0, stream>>>(c1out, hal2);
    conv2_lds<<<448, 128, 0, stream>>>(hal2, wb2, s2, bb2, hal3);
    conv3_lds<<<112, 256, 0, stream>>>(hal3, wb3, s3, bb3, hal4);
    conv4_lds<<<dim3(98, 3), 256, 0, stream>>>(hal4, wb4, s4, bb4, memv);

    // ---- attention K~ precompute: KT = mem @ attn_w ----
    kmat_lds<<<dim3(98, 3), 256, 0, stream>>>(memv, wattnTP, KT);

    // ---- sequential decoder (xin double-buffered) ----
    ushort_t* xcur = xinA;
    ushort_t* xnxt = xinB;
    for (int t = 0; t < NT; ++t) {
        attn2<<<dim3(NB, 2), NH, 0, stream>>>(xcur, KT, memv);
        step_fused<<<48, 256, 0, stream>>>(
            xcur, wcombP, eg + (size_t)t * NB * 3072, cbuf, hbuf, xnxt, HallP, t);
        ushort_t* tmp = xcur; xcur = xnxt; xnxt = tmp;
    }

    // ---- vocab projection for all 16 steps at once (+ h/c copy in epilogue) ----
    gemm_ldsb<1><<<1000, 256, 0, stream>>>(HallP, fcwb, fc_b, nullptr, out, NV, hbuf, cbuf);
}